// Round 1
// baseline (1811.683 us; speedup 1.0000x reference)
//
#include <hip/hip_runtime.h>
#include <hip/hip_bf16.h>

// RiemannianIFNode:
//   out0: s_seq [T=16, N=65536, D=256] spikes from integrate-and-fire scan
//   out1: z_out [N, D] Lorentz expmap
// Memory-bound: ~2.25 GB total traffic.

constexpr int T_STEPS = 16;

// ---------------- Kernel 1: integrate-and-fire scan ----------------
// One thread per float4 column; T=16 sequential accumulate (matches reference
// op order exactly -> bitwise-identical fp32 path).
__global__ __launch_bounds__(256) void if_scan_kernel(
    const float* __restrict__ x, float* __restrict__ s, int ndv /* (N*D)/4 */) {
    int i = blockIdx.x * blockDim.x + threadIdx.x;
    if (i >= ndv) return;
    const float4* __restrict__ x4 = (const float4*)x;
    float4* __restrict__ s4 = (float4*)s;

    float4 mem = make_float4(0.f, 0.f, 0.f, 0.f);
#pragma unroll
    for (int t = 0; t < T_STEPS; ++t) {
        float4 xt = x4[(size_t)t * ndv + i];
        float4 sp;
        mem.x += xt.x; sp.x = (mem.x > 1.0f) ? 1.0f : 0.0f; mem.x -= sp.x;
        mem.y += xt.y; sp.y = (mem.y > 1.0f) ? 1.0f : 0.0f; mem.y -= sp.y;
        mem.z += xt.z; sp.z = (mem.z > 1.0f) ? 1.0f : 0.0f; mem.z -= sp.z;
        mem.w += xt.w; sp.w = (mem.w > 1.0f) ? 1.0f : 0.0f; mem.w -= sp.w;
        s4[(size_t)t * ndv + i] = sp;
    }
}

// ---------------- Kernel 2: Lorentz expmap ----------------
// One wave (64 lanes) per row of D=256; lane holds float4. Shuffle-reduce the
// Minkowski inner product across the wave, then each lane writes its float4.
__global__ __launch_bounds__(256) void expmap_kernel(
    const float* __restrict__ v, const float* __restrict__ z,
    float* __restrict__ out, int nrows) {
    const int wave = threadIdx.x >> 6;   // 4 waves per block -> 4 rows
    const int lane = threadIdx.x & 63;
    const int row = blockIdx.x * 4 + wave;
    if (row >= nrows) return;

    const float4* __restrict__ v4 = (const float4*)v + (size_t)row * 64;
    const float4* __restrict__ z4 = (const float4*)z + (size_t)row * 64;
    float4* __restrict__ o4 = (float4*)out + (size_t)row * 64;

    float4 vv = v4[lane];
    float4 zz = z4[lane];

    // Minkowski inner <v,v>_L = -v0^2 + sum_{i>=1} vi^2
    float c = vv.x * vv.x + vv.y * vv.y + vv.z * vv.z + vv.w * vv.w;
    if (lane == 0) c -= 2.0f * vv.x * vv.x;

#pragma unroll
    for (int off = 32; off >= 1; off >>= 1) c += __shfl_xor(c, off, 64);

    float vnorm = sqrtf(fmaxf(c, 1e-8f));
    float e = expf(vnorm);
    float einv = 1.0f / e;
    float ch = 0.5f * (e + einv);           // cosh
    float sh = 0.5f * (e - einv) / vnorm;   // sinh / |v|

    float4 o;
    o.x = ch * zz.x + sh * vv.x;
    o.y = ch * zz.y + sh * vv.y;
    o.z = ch * zz.z + sh * vv.z;
    o.w = ch * zz.w + sh * vv.w;
    o4[lane] = o;
}

extern "C" void kernel_launch(void* const* d_in, const int* in_sizes, int n_in,
                              void* d_out, int out_size, void* d_ws, size_t ws_size,
                              hipStream_t stream) {
    const float* x_seq = (const float*)d_in[0];  // [T, N, D]
    const float* v_seq = (const float*)d_in[1];  // [N, D]
    const float* z_seq = (const float*)d_in[2];  // [N, D]
    float* out = (float*)d_out;

    const int nd = in_sizes[1];          // N*D = 16,777,216
    const int ndv = nd / 4;              // float4 count per timestep
    const int nrows = nd / 256;          // N (D = 256)

    float* s_out = out;                          // [T*N*D]
    float* z_out = out + (size_t)T_STEPS * nd;   // [N*D]

    // Kernel 1: IF scan
    {
        int threads = 256;
        int blocks = (ndv + threads - 1) / threads;
        if_scan_kernel<<<blocks, threads, 0, stream>>>(x_seq, s_out, ndv);
    }
    // Kernel 2: expmap (4 rows per 256-thread block)
    {
        int threads = 256;
        int blocks = (nrows + 3) / 4;
        expmap_kernel<<<blocks, threads, 0, stream>>>(v_seq, z_seq, z_out, nrows);
    }
}